// Round 11
// baseline (1252.805 us; speedup 1.0000x reference)
//
#include <hip/hip_runtime.h>
#include <hip/hip_bf16.h>

#define NODES 100000
#define BN_EPS 1e-5f
#define NB2 512          // buckets
#define NPB2 196         // nodes per bucket (512*196 = 100352 >= 100000)
#define CAP 6656         // slots per bucket (avg 6272, +4.8 sigma), 16-aligned
#define EPB 2048         // edges per place block (1563 blocks at E=3.2M)

__device__ __forceinline__ unsigned bf16rne(float f) {
    unsigned u = __float_as_uint(f);
    u += 0x7FFFu + ((u >> 16) & 1u);
    return u >> 16;
}
__device__ __forceinline__ float bflo(unsigned u) { return __uint_as_float(u << 16); }
__device__ __forceinline__ float bfhi(unsigned u) { return __uint_as_float(u & 0xFFFF0000u); }

// ---------------------------------------------------------------------------
// Placement into capacity-strided buckets (rounds 2-10 proven pattern,
// NB2=512). packed word = (r_local << 17) | g  (r_local < 196, g < 2^17).
// ---------------------------------------------------------------------------
__global__ __launch_bounds__(256, 8) void k_place(
        const int* __restrict__ ridx, const int* __restrict__ gidx,
        int* __restrict__ cursor, unsigned* __restrict__ packed, int E) {
    __shared__ int lh[4][NB2];
    const int t = threadIdx.x;
    const int w = t >> 6;
    for (int k = t; k < 4 * NB2; k += 256) ((int*)lh)[k] = 0;
    __syncthreads();
    const int base = blockIdx.x * EPB;
    int r[EPB / 256], g[EPB / 256];
#pragma unroll
    for (int k = 0; k < EPB / 256; ++k) {
        int e = base + t + (k << 8);
        r[k] = (e < E) ? ridx[e] : -1;
        g[k] = (e < E) ? gidx[e] : 0;
    }
#pragma unroll
    for (int k = 0; k < EPB / 256; ++k)
        if (r[k] >= 0) atomicAdd(&lh[w][(unsigned)r[k] / NPB2], 1);
    __syncthreads();
    for (int k = t; k < NB2; k += 256) {
        int c0 = lh[0][k], c1 = lh[1][k], c2 = lh[2][k], c3 = lh[3][k];
        int tot = c0 + c1 + c2 + c3;
        if (tot) {
            int g0 = k * CAP + atomicAdd(&cursor[k], tot);
            lh[0][k] = g0;
            lh[1][k] = g0 + c0;
            lh[2][k] = g0 + c0 + c1;
            lh[3][k] = g0 + c0 + c1 + c2;
        }
    }
    __syncthreads();
#pragma unroll
    for (int k = 0; k < EPB / 256; ++k) {
        if (r[k] >= 0) {
            unsigned rr = (unsigned)r[k];
            unsigned b = rr / NPB2;
            int off = atomicAdd(&lh[w][b], 1);
            if (off < (int)((b + 1) * CAP))   // capacity guard (P ~ 1e-5)
                packed[off] = ((rr - b * NPB2) << 17) | (unsigned)g[k];
        }
    }
}

// ---------------------------------------------------------------------------
// bf16 transpose/pack: x [64][N] fp32 -> xb [n][64ch] bf16 (128B rows).
// Linearity: segment_mean(W_n x_src) == W_n segment_mean(x_src).
// ---------------------------------------------------------------------------
__global__ __launch_bounds__(256, 4) void k_xpose(
        const float* __restrict__ x, unsigned* __restrict__ xb2) {
    __shared__ float lx[64 * 68];
    const int t = threadIdx.x;
    const int n0 = blockIdx.x * 64;
    for (int idx = t; idx < 1024; idx += 256) {
        int rr = idx >> 4;
        int q4 = (idx & 15) * 4;
        int n = n0 + q4;
        float4 xv = {0.f, 0.f, 0.f, 0.f};
        if (n < NODES) xv = *(const float4*)(x + (size_t)rr * NODES + n);
        *(float4*)&lx[rr * 68 + q4] = xv;
    }
    __syncthreads();
    const int c4 = (t & 15) * 4;
    const int j4 = (t >> 4) * 4;
    uint2* F2 = (uint2*)xb2;
#pragma unroll
    for (int k = 0; k < 4; ++k) {
        int n = n0 + j4 + k;
        if (n < NODES) {
            float v0 = lx[(c4 + 0) * 68 + j4 + k];
            float v1 = lx[(c4 + 1) * 68 + j4 + k];
            float v2 = lx[(c4 + 2) * 68 + j4 + k];
            float v3 = lx[(c4 + 3) * 68 + j4 + k];
            uint2 val;
            val.x = bf16rne(v0) | (bf16rne(v1) << 16);
            val.y = bf16rne(v2) | (bf16rne(v3) << 16);
            F2[n * 16 + (c4 >> 2)] = val;   // 128B contiguous across 16 lanes
        }
    }
}

// ---------------------------------------------------------------------------
// Fused segment-mean, one bucket per block: per-node fp32 accumulators in
// LDS (ds_add_f32), gathers bf16 x rows directly from place's bucket-grouped
// packed stream -- no node-level sort needed. acc stride 68 rotates the
// bank base by 4*r so concurrent sub-group adds spread across banks.
// 54 KB LDS -> 2 blocks/CU (grid 512) -> 32 waves/CU.
// ---------------------------------------------------------------------------
__global__ __launch_bounds__(1024) void k_segmean(
        const unsigned* __restrict__ xb, const unsigned* __restrict__ packed,
        const int* __restrict__ cursor, float* __restrict__ meanx) {
    __shared__ float acc[NPB2 * 68];   // 53,312 B
    __shared__ int lcnt[NPB2];
    const int b = blockIdx.x;
    const int t = threadIdx.x;
    for (int k = t; k < NPB2 * 17; k += 1024)
        ((float4*)acc)[k] = float4{0.f, 0.f, 0.f, 0.f};
    for (int k = t; k < NPB2; k += 1024) lcnt[k] = 0;
    __syncthreads();
    int cntb = cursor[b];
    if (cntb > CAP) cntb = CAP;
    const size_t s0b = (size_t)b * CAP;
    const int lane = t & 63;
    const int w = t >> 6;           // wave 0..15
    const int sub = lane >> 3;      // edge slot 0..7
    const int cp = lane & 7;        // uint4 slot (8 bf16 channels)
    for (int i = w * 16; i < cntb; i += 256) {
        int e0 = i + sub;
        int e1 = i + 8 + sub;
        if (e0 < cntb) {
            unsigned v = packed[s0b + e0];
            unsigned r = v >> 17, g = v & 0x1FFFFu;
            uint4 u = *(const uint4*)(xb + (((size_t)g) << 5) + (cp << 2));
            float* a = &acc[r * 68 + cp * 8];
            atomicAdd(&a[0], bflo(u.x)); atomicAdd(&a[1], bfhi(u.x));
            atomicAdd(&a[2], bflo(u.y)); atomicAdd(&a[3], bfhi(u.y));
            atomicAdd(&a[4], bflo(u.z)); atomicAdd(&a[5], bfhi(u.z));
            atomicAdd(&a[6], bflo(u.w)); atomicAdd(&a[7], bfhi(u.w));
            if (cp == 0) atomicAdd(&lcnt[r], 1);
        }
        if (e1 < cntb) {
            unsigned v = packed[s0b + e1];
            unsigned r = v >> 17, g = v & 0x1FFFFu;
            uint4 u = *(const uint4*)(xb + (((size_t)g) << 5) + (cp << 2));
            float* a = &acc[r * 68 + cp * 8];
            atomicAdd(&a[0], bflo(u.x)); atomicAdd(&a[1], bfhi(u.x));
            atomicAdd(&a[2], bflo(u.y)); atomicAdd(&a[3], bfhi(u.y));
            atomicAdd(&a[4], bflo(u.z)); atomicAdd(&a[5], bfhi(u.z));
            atomicAdd(&a[6], bflo(u.w)); atomicAdd(&a[7], bfhi(u.w));
            if (cp == 0) atomicAdd(&lcnt[r], 1);
        }
    }
    __syncthreads();
    // divide by count, write node-major meanx[n][64] (float4 coalesced)
    for (int k = t; k < NPB2 * 16; k += 1024) {
        int nl = k >> 4;
        int n = b * NPB2 + nl;
        if (n < NODES) {
            float inv = 1.f / fmaxf((float)lcnt[nl], 1.f);
            float4 v = *(const float4*)&acc[nl * 68 + (k & 15) * 4];
            v.x *= inv; v.y *= inv; v.z *= inv; v.w *= inv;
            *(float4*)(meanx + (size_t)n * 64 + (k & 15) * 4) = v;
        }
    }
}

// fp32 Fn variant (fallback path only)
__global__ __launch_bounds__(256) void k_gemm_n(
        const float* __restrict__ x, const float* __restrict__ wn,
        float* __restrict__ Fn) {
    __shared__ float lx[64][65];
    __shared__ float lw[64][65];
    const int t = threadIdx.x;
    const int n0 = blockIdx.x * 64;
    for (int idx = t; idx < 4096; idx += 256) {
        int r = idx >> 6, q = idx & 63;
        lw[r][q] = wn[idx];
        int n = n0 + q;
        lx[r][q] = (n < NODES) ? x[r * NODES + n] : 0.f;
    }
    __syncthreads();
    const int c = t & 63;
    const int jb = t >> 6;
    for (int k = 0; k < 16; ++k) {
        int j = jb + 4 * k;
        int n = n0 + j;
        if (n >= NODES) continue;
        float acc = 0.f;
#pragma unroll
        for (int ci = 0; ci < 64; ++ci)
            acc += lw[c][ci] * lx[ci][j];
        Fn[n * 64 + c] = acc;
    }
}

// ---------------------------------------------------------------------------
// Combine, K=128 via sequential restage (round-7/10 proven, ~61 us):
// phase A: acc = W_v . x; phase B: acc += W_n . meanx.
// Epilogue: BN partials via shfl+reds, LDS-transpose store.
// ---------------------------------------------------------------------------
__global__ __launch_bounds__(256, 4) void k_combine128(
        const float* __restrict__ x, const float* __restrict__ wv,
        const float* __restrict__ wn, const float* __restrict__ meanx,
        float* __restrict__ outpre, float* __restrict__ bn) {
    __shared__ float lx[64 * 68];
    __shared__ float wt[64 * 68];   // reused as tile[c*65+j] after FMA loops
    __shared__ float reds[64][5];
    __shared__ float redq[64][5];
    const int t = threadIdx.x;
    const int n0 = blockIdx.x * 64;
    const int c4 = (t & 15) * 4;
    const int j4 = (t >> 4) * 4;
    // ---- phase A: x tile + W_v
    for (int idx = t; idx < 1024; idx += 256) {
        int rr = idx >> 4;
        int q4 = (idx & 15) * 4;
        int n = n0 + q4;
        float4 xv = {0.f, 0.f, 0.f, 0.f};
        if (n < NODES) xv = *(const float4*)(x + (size_t)rr * NODES + n);
        *(float4*)&lx[rr * 68 + q4] = xv;
        float4 w4 = *(const float4*)(wv + (idx << 2));  // wv[co=rr][ci=q4..]
        wt[(q4 + 0) * 68 + rr] = w4.x;
        wt[(q4 + 1) * 68 + rr] = w4.y;
        wt[(q4 + 2) * 68 + rr] = w4.z;
        wt[(q4 + 3) * 68 + rr] = w4.w;
    }
    __syncthreads();
    float4 a0 = {0,0,0,0}, a1 = {0,0,0,0}, a2 = {0,0,0,0}, a3 = {0,0,0,0};
#pragma unroll 8
    for (int ci = 0; ci < 64; ++ci) {
        float4 w = *(const float4*)&wt[ci * 68 + c4];
        float4 xv = *(const float4*)&lx[ci * 68 + j4];
        a0.x += w.x * xv.x; a0.y += w.x * xv.y; a0.z += w.x * xv.z; a0.w += w.x * xv.w;
        a1.x += w.y * xv.x; a1.y += w.y * xv.y; a1.z += w.y * xv.z; a1.w += w.y * xv.w;
        a2.x += w.z * xv.x; a2.y += w.z * xv.y; a2.z += w.z * xv.z; a2.w += w.z * xv.w;
        a3.x += w.w * xv.x; a3.y += w.w * xv.y; a3.z += w.w * xv.z; a3.w += w.w * xv.w;
    }
    __syncthreads();
    // ---- phase B: meanx tile (transposed from node-major) + W_n
    for (int idx = t; idx < 1024; idx += 256) {
        int j  = idx >> 4;           // node offset 0..63
        int ci4 = (idx & 15) * 4;    // ci 0..60
        int n = n0 + j;
        float4 m4 = {0.f, 0.f, 0.f, 0.f};
        if (n < NODES) m4 = *(const float4*)(meanx + (size_t)n * 64 + ci4);
        lx[(ci4 + 0) * 68 + j] = m4.x;
        lx[(ci4 + 1) * 68 + j] = m4.y;
        lx[(ci4 + 2) * 68 + j] = m4.z;
        lx[(ci4 + 3) * 68 + j] = m4.w;
        int rr = idx >> 4;
        int q4 = (idx & 15) * 4;
        float4 w4 = *(const float4*)(wn + (idx << 2));  // wn[co=rr][ci=q4..]
        wt[(q4 + 0) * 68 + rr] = w4.x;
        wt[(q4 + 1) * 68 + rr] = w4.y;
        wt[(q4 + 2) * 68 + rr] = w4.z;
        wt[(q4 + 3) * 68 + rr] = w4.w;
    }
    __syncthreads();
#pragma unroll 8
    for (int ci = 0; ci < 64; ++ci) {
        float4 w = *(const float4*)&wt[ci * 68 + c4];
        float4 xv = *(const float4*)&lx[ci * 68 + j4];
        a0.x += w.x * xv.x; a0.y += w.x * xv.y; a0.z += w.x * xv.z; a0.w += w.x * xv.w;
        a1.x += w.y * xv.x; a1.y += w.y * xv.y; a1.z += w.y * xv.z; a1.w += w.y * xv.w;
        a2.x += w.z * xv.x; a2.y += w.z * xv.y; a2.z += w.z * xv.z; a2.w += w.z * xv.w;
        a3.x += w.w * xv.x; a3.y += w.w * xv.y; a3.z += w.w * xv.z; a3.w += w.w * xv.w;
    }
    __syncthreads();                 // wt dead for ALL waves; reuse as tile
    float* tile = wt;
    float ls0 = 0.f, ls1 = 0.f, ls2 = 0.f, ls3 = 0.f;
    float lq0 = 0.f, lq1 = 0.f, lq2 = 0.f, lq3 = 0.f;
#pragma unroll
    for (int k = 0; k < 4; ++k) {
        int j = j4 + k;
        int n = n0 + j;
        float v0 = 0.f, v1 = 0.f, v2 = 0.f, v3 = 0.f;
        if (n < NODES) {
            v0 = (k == 0) ? a0.x : (k == 1) ? a0.y : (k == 2) ? a0.z : a0.w;
            v1 = (k == 0) ? a1.x : (k == 1) ? a1.y : (k == 2) ? a1.z : a1.w;
            v2 = (k == 0) ? a2.x : (k == 1) ? a2.y : (k == 2) ? a2.z : a2.w;
            v3 = (k == 0) ? a3.x : (k == 1) ? a3.y : (k == 2) ? a3.z : a3.w;
            ls0 += v0; lq0 += v0 * v0;
            ls1 += v1; lq1 += v1 * v1;
            ls2 += v2; lq2 += v2 * v2;
            ls3 += v3; lq3 += v3 * v3;
        }
        tile[(c4 + 0) * 65 + j] = v0;
        tile[(c4 + 1) * 65 + j] = v1;
        tile[(c4 + 2) * 65 + j] = v2;
        tile[(c4 + 3) * 65 + j] = v3;
    }
    const int lane = t & 63;
    const int wid = t >> 6;
#pragma unroll
    for (int m = 16; m < 64; m <<= 1) {
        ls0 += __shfl_xor(ls0, m); lq0 += __shfl_xor(lq0, m);
        ls1 += __shfl_xor(ls1, m); lq1 += __shfl_xor(lq1, m);
        ls2 += __shfl_xor(ls2, m); lq2 += __shfl_xor(lq2, m);
        ls3 += __shfl_xor(ls3, m); lq3 += __shfl_xor(lq3, m);
    }
    if (lane < 16) {
        reds[lane * 4 + 0][wid] = ls0; redq[lane * 4 + 0][wid] = lq0;
        reds[lane * 4 + 1][wid] = ls1; redq[lane * 4 + 1][wid] = lq1;
        reds[lane * 4 + 2][wid] = ls2; redq[lane * 4 + 2][wid] = lq2;
        reds[lane * 4 + 3][wid] = ls3; redq[lane * 4 + 3][wid] = lq3;
    }
    __syncthreads();
    const int j2 = t & 63;
    const int c2 = t >> 6;
    const int n = n0 + j2;
    if (n < NODES) {
        for (int k = 0; k < 16; ++k) {
            int cc = c2 + 4 * k;
            outpre[cc * NODES + n] = tile[cc * 65 + j2];
        }
    }
    if (t < 64) {
        float s = reds[t][0] + reds[t][1] + reds[t][2] + reds[t][3];
        float q = redq[t][0] + redq[t][1] + redq[t][2] + redq[t][3];
        atomicAdd(&bn[t], s);
        atomicAdd(&bn[64 + t], q);
    }
}

// ---------------------------------------------------------------------------
// Fallback combine (round-2 proven): Fv GEMM + mean add (+divide).
// ---------------------------------------------------------------------------
__global__ __launch_bounds__(256, 4) void k_combine_fb(
        const float* __restrict__ x, const float* __restrict__ wv,
        const float* __restrict__ sums, const int* __restrict__ counts,
        const int divide,
        float* __restrict__ outpre, float* __restrict__ bn) {
    __shared__ float lx[64 * 68];
    __shared__ float wt[64 * 68];
    __shared__ float reds[64][5];
    __shared__ float redq[64][5];
    const int t = threadIdx.x;
    const int n0 = blockIdx.x * 64;
    const int c4 = (t & 15) * 4;
    const int j4 = (t >> 4) * 4;
    float4 mv[4];
    const float4* sums4 = (const float4*)sums;
#pragma unroll
    for (int k = 0; k < 4; ++k) {
        int n = n0 + j4 + k;
        mv[k] = (n < NODES) ? sums4[n * 16 + (c4 >> 2)]
                            : float4{0.f, 0.f, 0.f, 0.f};
    }
    for (int idx = t; idx < 1024; idx += 256) {
        int rr = idx >> 4;
        int q4 = (idx & 15) * 4;
        int n = n0 + q4;
        float4 xv = {0.f, 0.f, 0.f, 0.f};
        if (n < NODES) xv = *(const float4*)(x + (size_t)rr * NODES + n);
        *(float4*)&lx[rr * 68 + q4] = xv;
        float4 w4 = *(const float4*)(wv + (idx << 2));
        wt[(q4 + 0) * 68 + rr] = w4.x;
        wt[(q4 + 1) * 68 + rr] = w4.y;
        wt[(q4 + 2) * 68 + rr] = w4.z;
        wt[(q4 + 3) * 68 + rr] = w4.w;
    }
    __syncthreads();
    float4 a0 = {0,0,0,0}, a1 = {0,0,0,0}, a2 = {0,0,0,0}, a3 = {0,0,0,0};
#pragma unroll 8
    for (int ci = 0; ci < 64; ++ci) {
        float4 w = *(const float4*)&wt[ci * 68 + c4];
        float4 xv = *(const float4*)&lx[ci * 68 + j4];
        a0.x += w.x * xv.x; a0.y += w.x * xv.y; a0.z += w.x * xv.z; a0.w += w.x * xv.w;
        a1.x += w.y * xv.x; a1.y += w.y * xv.y; a1.z += w.y * xv.z; a1.w += w.y * xv.w;
        a2.x += w.z * xv.x; a2.y += w.z * xv.y; a2.z += w.z * xv.z; a2.w += w.z * xv.w;
        a3.x += w.w * xv.x; a3.y += w.w * xv.y; a3.z += w.w * xv.z; a3.w += w.w * xv.w;
    }
    __syncthreads();
    float* tile = wt;
    float ls0 = 0.f, ls1 = 0.f, ls2 = 0.f, ls3 = 0.f;
    float lq0 = 0.f, lq1 = 0.f, lq2 = 0.f, lq3 = 0.f;
#pragma unroll
    for (int k = 0; k < 4; ++k) {
        int j = j4 + k;
        int n = n0 + j;
        float v0 = 0.f, v1 = 0.f, v2 = 0.f, v3 = 0.f;
        if (n < NODES) {
            float4 m = mv[k];
            if (divide) {
                float cf = fmaxf((float)counts[n], 1.f);
                m.x /= cf; m.y /= cf; m.z /= cf; m.w /= cf;
            }
            float b0 = (k == 0) ? a0.x : (k == 1) ? a0.y : (k == 2) ? a0.z : a0.w;
            float b1 = (k == 0) ? a1.x : (k == 1) ? a1.y : (k == 2) ? a1.z : a1.w;
            float b2 = (k == 0) ? a2.x : (k == 1) ? a2.y : (k == 2) ? a2.z : a2.w;
            float b3 = (k == 0) ? a3.x : (k == 1) ? a3.y : (k == 2) ? a3.z : a3.w;
            v0 = m.x + b0; v1 = m.y + b1; v2 = m.z + b2; v3 = m.w + b3;
            ls0 += v0; lq0 += v0 * v0;
            ls1 += v1; lq1 += v1 * v1;
            ls2 += v2; lq2 += v2 * v2;
            ls3 += v3; lq3 += v3 * v3;
        }
        tile[(c4 + 0) * 65 + j] = v0;
        tile[(c4 + 1) * 65 + j] = v1;
        tile[(c4 + 2) * 65 + j] = v2;
        tile[(c4 + 3) * 65 + j] = v3;
    }
    const int lane = t & 63;
    const int wid = t >> 6;
#pragma unroll
    for (int m = 16; m < 64; m <<= 1) {
        ls0 += __shfl_xor(ls0, m); lq0 += __shfl_xor(lq0, m);
        ls1 += __shfl_xor(ls1, m); lq1 += __shfl_xor(lq1, m);
        ls2 += __shfl_xor(ls2, m); lq2 += __shfl_xor(lq2, m);
        ls3 += __shfl_xor(ls3, m); lq3 += __shfl_xor(lq3, m);
    }
    if (lane < 16) {
        reds[lane * 4 + 0][wid] = ls0; redq[lane * 4 + 0][wid] = lq0;
        reds[lane * 4 + 1][wid] = ls1; redq[lane * 4 + 1][wid] = lq1;
        reds[lane * 4 + 2][wid] = ls2; redq[lane * 4 + 2][wid] = lq2;
        reds[lane * 4 + 3][wid] = ls3; redq[lane * 4 + 3][wid] = lq3;
    }
    __syncthreads();
    const int j2 = t & 63;
    const int c2 = t >> 6;
    const int n = n0 + j2;
    if (n < NODES) {
        for (int k = 0; k < 16; ++k) {
            int cc = c2 + 4 * k;
            outpre[cc * NODES + n] = tile[cc * 65 + j2];
        }
    }
    if (t < 64) {
        float s = reds[t][0] + reds[t][1] + reds[t][2] + reds[t][3];
        float q = redq[t][0] + redq[t][1] + redq[t][2] + redq[t][3];
        atomicAdd(&bn[t], s);
        atomicAdd(&bn[64 + t], q);
    }
}

// K4: per-channel affine from batch stats + PReLU, float4 per thread.
__global__ __launch_bounds__(256) void k_final(
        float* __restrict__ out, const float* __restrict__ bn,
        const float* __restrict__ gamma, const float* __restrict__ beta,
        const float* __restrict__ pa) {
    const int c = blockIdx.y;
    const int i4 = (blockIdx.x * 256 + threadIdx.x) * 4;
    const float invN = 1.f / (float)NODES;
    float mu = bn[c] * invN;
    float var = fmaxf(bn[64 + c] * invN - mu * mu, 0.f);
    float scale = gamma[c] * rsqrtf(var + BN_EPS);
    float shift = beta[c] - mu * scale;
    float a = pa[0];
    if (i4 < NODES) {   // NODES % 4 == 0 -> full float4 valid
        float4 y = *(float4*)(out + (size_t)c * NODES + i4);
        y.x = y.x * scale + shift; y.x = (y.x >= 0.f) ? y.x : a * y.x;
        y.y = y.y * scale + shift; y.y = (y.y >= 0.f) ? y.y : a * y.y;
        y.z = y.z * scale + shift; y.z = (y.z >= 0.f) ? y.z : a * y.z;
        y.w = y.w * scale + shift; y.w = (y.w >= 0.f) ? y.w : a * y.w;
        *(float4*)(out + (size_t)c * NODES + i4) = y;
    }
}

// Fallback (ws too small): atomic scatter, node-major sums (round-2 proven).
__global__ __launch_bounds__(256) void k_scatter(
        const float* __restrict__ Fn,
        const int* __restrict__ gidx, const int* __restrict__ ridx,
        float* __restrict__ sums, int* __restrict__ counts, int E) {
    const int wave = (int)((blockIdx.x * blockDim.x + threadIdx.x) >> 6);
    const int lane = threadIdx.x & 63;
    const int base = wave * 64;
    if (base >= E) return;
    const int nvalid = min(64, E - base);
    int g = 0, r = 0;
    if (lane < nvalid) {
        g = gidx[base + lane];
        r = ridx[base + lane];
        atomicAdd(&counts[r], 1);
    }
    for (int i = 0; i < nvalid; ++i) {
        int gg = __shfl(g, i);
        int rr = __shfl(r, i);
        float v = Fn[gg * 64 + lane];
        atomicAdd(&sums[rr * 64 + lane], v);
    }
}

extern "C" void kernel_launch(void* const* d_in, const int* in_sizes, int n_in,
                              void* d_out, int out_size, void* d_ws, size_t ws_size,
                              hipStream_t stream) {
    const float* x     = (const float*)d_in[0];
    const float* w_v   = (const float*)d_in[1];
    const float* w_n   = (const float*)d_in[2];
    const float* gamma = (const float*)d_in[3];
    const float* beta  = (const float*)d_in[4];
    const float* pa    = (const float*)d_in[5];
    const int* ridx    = (const int*)d_in[6];
    const int* gidx    = (const int*)d_in[7];
    float* out = (float*)d_out;

    const int E = in_sizes[6];
    const long long N64 = (long long)NODES * 64;
    const int ntiles = (NODES + 63) / 64;
    const dim3 g4((NODES / 4 + 255) / 256, 64);   // float4 k_final

    // Main ws (words): meanx[N64] | packed[512*CAP] | cursor[512] | bn[128]
    //                  = 6.4M + 3.408M + 640 = 9.808M words (39.2 MB)
    size_t need = ((size_t)N64 + (size_t)NB2 * CAP + NB2 + 128) * 4;

    if (ws_size >= need) {
        float*    meanx  = (float*)d_ws;
        unsigned* packed = (unsigned*)(meanx + N64);
        int*      cursor = (int*)(packed + (size_t)NB2 * CAP);
        float*    bn     = (float*)(cursor + NB2);
        unsigned* xb = (unsigned*)out;  // 12.8 MB bf16 x rows staged in d_out

        hipMemsetAsync(cursor, 0, (NB2 + 128) * sizeof(int), stream);
        k_place<<<(E + EPB - 1) / EPB, 256, 0, stream>>>(ridx, gidx, cursor,
                                                         packed, E);
        k_xpose<<<ntiles, 256, 0, stream>>>(x, xb);
        k_segmean<<<NB2, 1024, 0, stream>>>(xb, packed, cursor, meanx);
        k_combine128<<<ntiles, 256, 0, stream>>>(x, w_v, w_n, meanx, out, bn);
        k_final<<<g4, 256, 0, stream>>>(out, bn, gamma, beta, pa);
    } else {
        // Fallback: atomic-scatter path (26.0 MB ws), round-2 proven chain.
        float* sums   = (float*)d_ws;
        int*   counts = (int*)(sums + N64);
        float* bn     = (float*)(sums + N64 + NODES);
        float* Fn = out;

        hipMemsetAsync(sums, 0, (size_t)(N64 + NODES + 128) * sizeof(float),
                       stream);
        k_gemm_n<<<ntiles, 256, 0, stream>>>(x, w_n, Fn);
        k_scatter<<<(E + 255) / 256, 256, 0, stream>>>(Fn, gidx, ridx, sums,
                                                       counts, E);
        k_combine_fb<<<ntiles, 256, 0, stream>>>(x, w_v, sums, counts, 1, out, bn);
        k_final<<<g4, 256, 0, stream>>>(out, bn, gamma, beta, pa);
    }
}

// Round 12
// 274.737 us; speedup vs baseline: 4.5600x; 4.5600x over previous
//
#include <hip/hip_runtime.h>
#include <hip/hip_bf16.h>

#define NODES 100000
#define BN_EPS 1e-5f
#define NB2 256          // coarse buckets
#define NPB2 391         // nodes per bucket (256*391 = 100096 >= 100000)
#define CAP 13072        // slots per bucket (avg 12512, +5 sigma), 16-aligned

__device__ __forceinline__ unsigned bf16rne(float f) {
    unsigned u = __float_as_uint(f);
    u += 0x7FFFu + ((u >> 16) & 1u);
    return u >> 16;
}
__device__ __forceinline__ float bflo(unsigned u) { return __uint_as_float(u << 16); }
__device__ __forceinline__ float bfhi(unsigned u) { return __uint_as_float(u & 0xFFFF0000u); }

// ---------------------------------------------------------------------------
// Placement, persistent-block two-pass: 256 blocks x 1024 threads, each owns
// ~12.5K consecutive edges. Pass 1: LDS hist (4-way split). Claim contiguous
// bucket ranges. Pass 2: re-read chunk (L2-resident, 100KB/block) + scatter.
// Runs per bucket per block ~49 words -> write-allocate ~17MB (was 46MB at
// EPB=2048: 8-word runs).
// ---------------------------------------------------------------------------
__global__ __launch_bounds__(1024) void k_place(
        const int* __restrict__ ridx, const int* __restrict__ gidx,
        int* __restrict__ cursor, unsigned* __restrict__ packed, int E) {
    __shared__ int lh[4][NB2];
    const int t = threadIdx.x;
    const int w = (t >> 6) & 3;
    for (int k = t; k < 4 * NB2; k += 1024) ((int*)lh)[k] = 0;
    __syncthreads();
    const int chunk = (E + gridDim.x - 1) / gridDim.x;
    const int lo = blockIdx.x * chunk;
    const int hi = min(E, lo + chunk);
    for (int e = lo + t; e < hi; e += 1024)
        atomicAdd(&lh[w][(unsigned)ridx[e] / NPB2], 1);
    __syncthreads();
    if (t < NB2) {
        int c0 = lh[0][t], c1 = lh[1][t], c2 = lh[2][t], c3 = lh[3][t];
        int tot = c0 + c1 + c2 + c3;
        if (tot) {
            int g0 = t * CAP + atomicAdd(&cursor[t], tot);
            lh[0][t] = g0;
            lh[1][t] = g0 + c0;
            lh[2][t] = g0 + c0 + c1;
            lh[3][t] = g0 + c0 + c1 + c2;
        }
    }
    __syncthreads();
    for (int e = lo + t; e < hi; e += 1024) {
        unsigned rr = (unsigned)ridx[e];       // L2 hit (re-read)
        unsigned g  = (unsigned)gidx[e];
        unsigned b  = rr / NPB2;
        int off = atomicAdd(&lh[w][b], 1);
        if (off < (int)((b + 1) * CAP))        // capacity guard (P ~ 1e-5)
            packed[off] = ((rr - b * NPB2) << 17) | g;
    }
}

// ---------------------------------------------------------------------------
// Bucket sort (round-10 proven): 4-way LDS sub-histograms, shfl-based scan,
// 4-way scatter cursors. In place within the bucket's L2-resident region.
// ---------------------------------------------------------------------------
__global__ __launch_bounds__(1024) void k_sortb(
        const int* __restrict__ cursor, unsigned* __restrict__ packed,
        int* __restrict__ nodestart, int* __restrict__ cnt) {
    __shared__ int lh[4][1024];   // 16 KB: sub-hists, then scatter cursors
    __shared__ int lw[16];
    const int b = blockIdx.x, t = threadIdx.x;
    const int w = t >> 8;         // thread-group 0..3
    const int s0b = b * CAP;
    int cntb = cursor[b];         // cursor holds the count
    if (cntb > CAP) cntb = CAP;
    unsigned r[(CAP + 1023) / 1024];  // 13, statically indexed
#pragma unroll
    for (int kk = 0; kk < (CAP + 1023) / 1024; ++kk) {
        int k = t + kk * 1024;
        if (k < cntb) r[kk] = packed[s0b + k];
    }
    lh[0][t] = 0; lh[1][t] = 0; lh[2][t] = 0; lh[3][t] = 0;
    __syncthreads();
#pragma unroll
    for (int kk = 0; kk < (CAP + 1023) / 1024; ++kk) {
        int k = t + kk * 1024;
        if (k < cntb) atomicAdd(&lh[w][r[kk] >> 17], 1);
    }
    __syncthreads();
    // per-bin totals + exclusive scan (shfl per-wave, lw cross-wave)
    int c0 = lh[0][t], c1 = lh[1][t], c2 = lh[2][t], c3 = lh[3][t];
    int c = c0 + c1 + c2 + c3;
    const int lane = t & 63;
    const int wid = t >> 6;
    int v = c;
#pragma unroll
    for (int off = 1; off < 64; off <<= 1) {
        int u = __shfl_up(v, off);
        if (lane >= off) v += u;
    }
    if (lane == 63) lw[wid] = v;
    __syncthreads();
    if (t == 0) {
        int s = 0;
#pragma unroll
        for (int i = 0; i < 16; ++i) { int x = lw[i]; lw[i] = s; s += x; }
    }
    __syncthreads();
    const int excl = v - c + lw[wid];
    if (t < NPB2) {
        int n = b * NPB2 + t;
        if (n < NODES) {
            nodestart[n] = s0b + excl;
            cnt[n] = c;
        }
    }
    // cursor init: thread t writes only its own lh[*][t] (no cross hazard)
    lh[0][t] = s0b + excl;
    lh[1][t] = s0b + excl + c0;
    lh[2][t] = s0b + excl + c0 + c1;
    lh[3][t] = s0b + excl + c0 + c1 + c2;
    __syncthreads();
#pragma unroll
    for (int kk = 0; kk < (CAP + 1023) / 1024; ++kk) {
        int k = t + kk * 1024;
        if (k < cntb) {
            unsigned val = r[kk];
            int pos = atomicAdd(&lh[w][val >> 17], 1);
            packed[pos] = val & 0x1FFFFu;   // pos includes s0b
        }
    }
}

// ---------------------------------------------------------------------------
// bf16 transpose/pack: x [64][N] fp32 -> xb [n][64ch] bf16 (128B rows).
// Linearity: segment_mean(W_n x_src) == W_n segment_mean(x_src).
// ---------------------------------------------------------------------------
__global__ __launch_bounds__(256, 4) void k_xpose(
        const float* __restrict__ x, unsigned* __restrict__ xb2) {
    __shared__ float lx[64 * 68];
    const int t = threadIdx.x;
    const int n0 = blockIdx.x * 64;
    for (int idx = t; idx < 1024; idx += 256) {
        int rr = idx >> 4;
        int q4 = (idx & 15) * 4;
        int n = n0 + q4;
        float4 xv = {0.f, 0.f, 0.f, 0.f};
        if (n < NODES) xv = *(const float4*)(x + (size_t)rr * NODES + n);
        *(float4*)&lx[rr * 68 + q4] = xv;
    }
    __syncthreads();
    const int c4 = (t & 15) * 4;
    const int j4 = (t >> 4) * 4;
    uint2* F2 = (uint2*)xb2;
#pragma unroll
    for (int k = 0; k < 4; ++k) {
        int n = n0 + j4 + k;
        if (n < NODES) {
            float v0 = lx[(c4 + 0) * 68 + j4 + k];
            float v1 = lx[(c4 + 1) * 68 + j4 + k];
            float v2 = lx[(c4 + 2) * 68 + j4 + k];
            float v3 = lx[(c4 + 3) * 68 + j4 + k];
            uint2 val;
            val.x = bf16rne(v0) | (bf16rne(v1) << 16);
            val.y = bf16rne(v2) | (bf16rne(v3) << 16);
            F2[n * 16 + (c4 >> 2)] = val;   // 128B contiguous across 16 lanes
        }
    }
}

// fp32 Fn variant (fallback path only)
__global__ __launch_bounds__(256) void k_gemm_n(
        const float* __restrict__ x, const float* __restrict__ wn,
        float* __restrict__ Fn) {
    __shared__ float lx[64][65];
    __shared__ float lw[64][65];
    const int t = threadIdx.x;
    const int n0 = blockIdx.x * 64;
    for (int idx = t; idx < 4096; idx += 256) {
        int r = idx >> 6, q = idx & 63;
        lw[r][q] = wn[idx];
        int n = n0 + q;
        lx[r][q] = (n < NODES) ? x[r * NODES + n] : 0.f;
    }
    __syncthreads();
    const int c = t & 63;
    const int jb = t >> 6;
    for (int k = 0; k < 16; ++k) {
        int j = jb + 4 * k;
        int n = n0 + j;
        if (n >= NODES) continue;
        float acc = 0.f;
#pragma unroll
        for (int ci = 0; ci < 64; ++ci)
            acc += lw[c][ci] * lx[ci][j];
        Fn[n * 64 + c] = acc;
    }
}

// ---------------------------------------------------------------------------
// Pull segment-mean: one wave per node, 8 lanes per edge, dwordx4 gathers
// (round-2 proven 55.5 us). Gathers bf16 x rows; output node-major [n][64].
// ---------------------------------------------------------------------------
__global__ __launch_bounds__(256) void k_segreduce(
        const unsigned* __restrict__ Fnh2, const unsigned* __restrict__ packed,
        const int* __restrict__ nodestart, const int* __restrict__ cnt,
        float4* __restrict__ mean4) {
    const int n = (int)((blockIdx.x * 256u + threadIdx.x) >> 6);
    if (n >= NODES) return;
    const int lane = threadIdx.x & 63;
    const int sub = lane >> 3;      // edge slot 0..7
    const int cp  = lane & 7;       // 8 lanes per edge, dwordx4 each
    const int s0 = nodestart[n];
    const int cn = cnt[n];
    const int s1 = s0 + cn;
    float f0 = 0.f, f1 = 0.f, f2 = 0.f, f3 = 0.f;
    float f4 = 0.f, f5 = 0.f, f6 = 0.f, f7 = 0.f;
    int i = s0;
    for (; i + 15 < s1; i += 16) {
        int ga = (int)packed[i + sub];
        int gb = (int)packed[i + 8 + sub];
        uint4 ua = *(const uint4*)(Fnh2 + (((size_t)ga) << 5) + (cp << 2));
        uint4 ub = *(const uint4*)(Fnh2 + (((size_t)gb) << 5) + (cp << 2));
        f0 += bflo(ua.x) + bflo(ub.x);
        f1 += bfhi(ua.x) + bfhi(ub.x);
        f2 += bflo(ua.y) + bflo(ub.y);
        f3 += bfhi(ua.y) + bfhi(ub.y);
        f4 += bflo(ua.z) + bflo(ub.z);
        f5 += bfhi(ua.z) + bfhi(ub.z);
        f6 += bflo(ua.w) + bflo(ub.w);
        f7 += bfhi(ua.w) + bfhi(ub.w);
    }
    for (; i < s1; i += 8) {
        uint4 u = {0u, 0u, 0u, 0u};
        if (i + sub < s1) {
            int g = (int)packed[i + sub];
            u = *(const uint4*)(Fnh2 + (((size_t)g) << 5) + (cp << 2));
        }
        f0 += bflo(u.x); f1 += bfhi(u.x);
        f2 += bflo(u.y); f3 += bfhi(u.y);
        f4 += bflo(u.z); f5 += bfhi(u.z);
        f6 += bflo(u.w); f7 += bfhi(u.w);
    }
#pragma unroll
    for (int m = 8; m < 64; m <<= 1) {
        f0 += __shfl_xor(f0, m);
        f1 += __shfl_xor(f1, m);
        f2 += __shfl_xor(f2, m);
        f3 += __shfl_xor(f3, m);
        f4 += __shfl_xor(f4, m);
        f5 += __shfl_xor(f5, m);
        f6 += __shfl_xor(f6, m);
        f7 += __shfl_xor(f7, m);
    }
    if (sub == 0) {
        float inv = 1.f / fmaxf((float)cn, 1.f);
        float4 lo4, hi4;
        lo4.x = f0 * inv; lo4.y = f1 * inv; lo4.z = f2 * inv; lo4.w = f3 * inv;
        hi4.x = f4 * inv; hi4.y = f5 * inv; hi4.z = f6 * inv; hi4.w = f7 * inv;
        mean4[n * 16 + cp * 2]     = lo4;
        mean4[n * 16 + cp * 2 + 1] = hi4;
    }
}

// ---------------------------------------------------------------------------
// Combine, K=128 via sequential restage (round-7 staging/FMA, proven).
// NEW epilogue: a0..a3 are (channel c4+q) x (nodes j4..j4+3) float4s ->
// stored DIRECTLY channel-major (coalesced 256B/channel/block); BN partials
// from the same registers. Deletes LDS transpose tile + one barrier.
// ---------------------------------------------------------------------------
__global__ __launch_bounds__(256, 4) void k_combine128(
        const float* __restrict__ x, const float* __restrict__ wv,
        const float* __restrict__ wn, const float* __restrict__ meanx,
        float* __restrict__ outpre, float* __restrict__ bn) {
    __shared__ float lx[64 * 68];
    __shared__ float wt[64 * 68];
    __shared__ float reds[64][5];
    __shared__ float redq[64][5];
    const int t = threadIdx.x;
    const int n0 = blockIdx.x * 64;
    const int c4 = (t & 15) * 4;
    const int j4 = (t >> 4) * 4;
    // ---- phase A: x tile + W_v
    for (int idx = t; idx < 1024; idx += 256) {
        int rr = idx >> 4;
        int q4 = (idx & 15) * 4;
        int n = n0 + q4;
        float4 xv = {0.f, 0.f, 0.f, 0.f};
        if (n < NODES) xv = *(const float4*)(x + (size_t)rr * NODES + n);
        *(float4*)&lx[rr * 68 + q4] = xv;
        float4 w4 = *(const float4*)(wv + (idx << 2));  // wv[co=rr][ci=q4..]
        wt[(q4 + 0) * 68 + rr] = w4.x;
        wt[(q4 + 1) * 68 + rr] = w4.y;
        wt[(q4 + 2) * 68 + rr] = w4.z;
        wt[(q4 + 3) * 68 + rr] = w4.w;
    }
    __syncthreads();
    float4 a0 = {0,0,0,0}, a1 = {0,0,0,0}, a2 = {0,0,0,0}, a3 = {0,0,0,0};
#pragma unroll 8
    for (int ci = 0; ci < 64; ++ci) {
        float4 w = *(const float4*)&wt[ci * 68 + c4];
        float4 xv = *(const float4*)&lx[ci * 68 + j4];
        a0.x += w.x * xv.x; a0.y += w.x * xv.y; a0.z += w.x * xv.z; a0.w += w.x * xv.w;
        a1.x += w.y * xv.x; a1.y += w.y * xv.y; a1.z += w.y * xv.z; a1.w += w.y * xv.w;
        a2.x += w.z * xv.x; a2.y += w.z * xv.y; a2.z += w.z * xv.z; a2.w += w.z * xv.w;
        a3.x += w.w * xv.x; a3.y += w.w * xv.y; a3.z += w.w * xv.z; a3.w += w.w * xv.w;
    }
    __syncthreads();
    // ---- phase B: meanx tile (transposed from node-major) + W_n
    for (int idx = t; idx < 1024; idx += 256) {
        int j  = idx >> 4;           // node offset 0..63
        int ci4 = (idx & 15) * 4;    // ci 0..60
        int n = n0 + j;
        float4 m4 = {0.f, 0.f, 0.f, 0.f};
        if (n < NODES) m4 = *(const float4*)(meanx + (size_t)n * 64 + ci4);
        lx[(ci4 + 0) * 68 + j] = m4.x;
        lx[(ci4 + 1) * 68 + j] = m4.y;
        lx[(ci4 + 2) * 68 + j] = m4.z;
        lx[(ci4 + 3) * 68 + j] = m4.w;
        int rr = idx >> 4;
        int q4 = (idx & 15) * 4;
        float4 w4 = *(const float4*)(wn + (idx << 2));  // wn[co=rr][ci=q4..]
        wt[(q4 + 0) * 68 + rr] = w4.x;
        wt[(q4 + 1) * 68 + rr] = w4.y;
        wt[(q4 + 2) * 68 + rr] = w4.z;
        wt[(q4 + 3) * 68 + rr] = w4.w;
    }
    __syncthreads();
#pragma unroll 8
    for (int ci = 0; ci < 64; ++ci) {
        float4 w = *(const float4*)&wt[ci * 68 + c4];
        float4 xv = *(const float4*)&lx[ci * 68 + j4];
        a0.x += w.x * xv.x; a0.y += w.x * xv.y; a0.z += w.x * xv.z; a0.w += w.x * xv.w;
        a1.x += w.y * xv.x; a1.y += w.y * xv.y; a1.z += w.y * xv.z; a1.w += w.y * xv.w;
        a2.x += w.z * xv.x; a2.y += w.z * xv.y; a2.z += w.z * xv.z; a2.w += w.z * xv.w;
        a3.x += w.w * xv.x; a3.y += w.w * xv.y; a3.z += w.w * xv.z; a3.w += w.w * xv.w;
    }
    // ---- epilogue: direct channel-major float4 stores + BN partials.
    // (acc is exactly 0 for n >= NODES: x and meanx staged as 0 there.)
    const int nj = n0 + j4;
    if (nj < NODES) {   // NODES%4==0 -> full float4 valid
        *(float4*)(outpre + (size_t)(c4 + 0) * NODES + nj) = a0;
        *(float4*)(outpre + (size_t)(c4 + 1) * NODES + nj) = a1;
        *(float4*)(outpre + (size_t)(c4 + 2) * NODES + nj) = a2;
        *(float4*)(outpre + (size_t)(c4 + 3) * NODES + nj) = a3;
    }
    float ls0 = a0.x + a0.y + a0.z + a0.w;
    float ls1 = a1.x + a1.y + a1.z + a1.w;
    float ls2 = a2.x + a2.y + a2.z + a2.w;
    float ls3 = a3.x + a3.y + a3.z + a3.w;
    float lq0 = a0.x*a0.x + a0.y*a0.y + a0.z*a0.z + a0.w*a0.w;
    float lq1 = a1.x*a1.x + a1.y*a1.y + a1.z*a1.z + a1.w*a1.w;
    float lq2 = a2.x*a2.x + a2.y*a2.y + a2.z*a2.z + a2.w*a2.w;
    float lq3 = a3.x*a3.x + a3.y*a3.y + a3.z*a3.z + a3.w*a3.w;
    const int lane = t & 63;
    const int wid = t >> 6;
#pragma unroll
    for (int m = 16; m < 64; m <<= 1) {
        ls0 += __shfl_xor(ls0, m); lq0 += __shfl_xor(lq0, m);
        ls1 += __shfl_xor(ls1, m); lq1 += __shfl_xor(lq1, m);
        ls2 += __shfl_xor(ls2, m); lq2 += __shfl_xor(lq2, m);
        ls3 += __shfl_xor(ls3, m); lq3 += __shfl_xor(lq3, m);
    }
    if (lane < 16) {
        reds[lane * 4 + 0][wid] = ls0; redq[lane * 4 + 0][wid] = lq0;
        reds[lane * 4 + 1][wid] = ls1; redq[lane * 4 + 1][wid] = lq1;
        reds[lane * 4 + 2][wid] = ls2; redq[lane * 4 + 2][wid] = lq2;
        reds[lane * 4 + 3][wid] = ls3; redq[lane * 4 + 3][wid] = lq3;
    }
    __syncthreads();
    if (t < 64) {
        float s = reds[t][0] + reds[t][1] + reds[t][2] + reds[t][3];
        float q = redq[t][0] + redq[t][1] + redq[t][2] + redq[t][3];
        atomicAdd(&bn[t], s);
        atomicAdd(&bn[64 + t], q);
    }
}

// ---------------------------------------------------------------------------
// Fallback combine (round-2 proven): Fv GEMM + mean add (+divide).
// ---------------------------------------------------------------------------
__global__ __launch_bounds__(256, 4) void k_combine_fb(
        const float* __restrict__ x, const float* __restrict__ wv,
        const float* __restrict__ sums, const int* __restrict__ counts,
        const int divide,
        float* __restrict__ outpre, float* __restrict__ bn) {
    __shared__ float lx[64 * 68];
    __shared__ float wt[64 * 68];
    __shared__ float reds[64][5];
    __shared__ float redq[64][5];
    const int t = threadIdx.x;
    const int n0 = blockIdx.x * 64;
    const int c4 = (t & 15) * 4;
    const int j4 = (t >> 4) * 4;
    float4 mv[4];
    const float4* sums4 = (const float4*)sums;
#pragma unroll
    for (int k = 0; k < 4; ++k) {
        int n = n0 + j4 + k;
        mv[k] = (n < NODES) ? sums4[n * 16 + (c4 >> 2)]
                            : float4{0.f, 0.f, 0.f, 0.f};
    }
    for (int idx = t; idx < 1024; idx += 256) {
        int rr = idx >> 4;
        int q4 = (idx & 15) * 4;
        int n = n0 + q4;
        float4 xv = {0.f, 0.f, 0.f, 0.f};
        if (n < NODES) xv = *(const float4*)(x + (size_t)rr * NODES + n);
        *(float4*)&lx[rr * 68 + q4] = xv;
        float4 w4 = *(const float4*)(wv + (idx << 2));
        wt[(q4 + 0) * 68 + rr] = w4.x;
        wt[(q4 + 1) * 68 + rr] = w4.y;
        wt[(q4 + 2) * 68 + rr] = w4.z;
        wt[(q4 + 3) * 68 + rr] = w4.w;
    }
    __syncthreads();
    float4 a0 = {0,0,0,0}, a1 = {0,0,0,0}, a2 = {0,0,0,0}, a3 = {0,0,0,0};
#pragma unroll 8
    for (int ci = 0; ci < 64; ++ci) {
        float4 w = *(const float4*)&wt[ci * 68 + c4];
        float4 xv = *(const float4*)&lx[ci * 68 + j4];
        a0.x += w.x * xv.x; a0.y += w.x * xv.y; a0.z += w.x * xv.z; a0.w += w.x * xv.w;
        a1.x += w.y * xv.x; a1.y += w.y * xv.y; a1.z += w.y * xv.z; a1.w += w.y * xv.w;
        a2.x += w.z * xv.x; a2.y += w.z * xv.y; a2.z += w.z * xv.z; a2.w += w.z * xv.w;
        a3.x += w.w * xv.x; a3.y += w.w * xv.y; a3.z += w.w * xv.z; a3.w += w.w * xv.w;
    }
    __syncthreads();
    float* tile = wt;
    float ls0 = 0.f, ls1 = 0.f, ls2 = 0.f, ls3 = 0.f;
    float lq0 = 0.f, lq1 = 0.f, lq2 = 0.f, lq3 = 0.f;
#pragma unroll
    for (int k = 0; k < 4; ++k) {
        int j = j4 + k;
        int n = n0 + j;
        float v0 = 0.f, v1 = 0.f, v2 = 0.f, v3 = 0.f;
        if (n < NODES) {
            float4 m = mv[k];
            if (divide) {
                float cf = fmaxf((float)counts[n], 1.f);
                m.x /= cf; m.y /= cf; m.z /= cf; m.w /= cf;
            }
            float b0 = (k == 0) ? a0.x : (k == 1) ? a0.y : (k == 2) ? a0.z : a0.w;
            float b1 = (k == 0) ? a1.x : (k == 1) ? a1.y : (k == 2) ? a1.z : a1.w;
            float b2 = (k == 0) ? a2.x : (k == 1) ? a2.y : (k == 2) ? a2.z : a2.w;
            float b3 = (k == 0) ? a3.x : (k == 1) ? a3.y : (k == 2) ? a3.z : a3.w;
            v0 = m.x + b0; v1 = m.y + b1; v2 = m.z + b2; v3 = m.w + b3;
            ls0 += v0; lq0 += v0 * v0;
            ls1 += v1; lq1 += v1 * v1;
            ls2 += v2; lq2 += v2 * v2;
            ls3 += v3; lq3 += v3 * v3;
        }
        tile[(c4 + 0) * 65 + j] = v0;
        tile[(c4 + 1) * 65 + j] = v1;
        tile[(c4 + 2) * 65 + j] = v2;
        tile[(c4 + 3) * 65 + j] = v3;
    }
    const int lane = t & 63;
    const int wid = t >> 6;
#pragma unroll
    for (int m = 16; m < 64; m <<= 1) {
        ls0 += __shfl_xor(ls0, m); lq0 += __shfl_xor(lq0, m);
        ls1 += __shfl_xor(ls1, m); lq1 += __shfl_xor(lq1, m);
        ls2 += __shfl_xor(ls2, m); lq2 += __shfl_xor(lq2, m);
        ls3 += __shfl_xor(ls3, m); lq3 += __shfl_xor(lq3, m);
    }
    if (lane < 16) {
        reds[lane * 4 + 0][wid] = ls0; redq[lane * 4 + 0][wid] = lq0;
        reds[lane * 4 + 1][wid] = ls1; redq[lane * 4 + 1][wid] = lq1;
        reds[lane * 4 + 2][wid] = ls2; redq[lane * 4 + 2][wid] = lq2;
        reds[lane * 4 + 3][wid] = ls3; redq[lane * 4 + 3][wid] = lq3;
    }
    __syncthreads();
    const int j2 = t & 63;
    const int c2 = t >> 6;
    const int n = n0 + j2;
    if (n < NODES) {
        for (int k = 0; k < 16; ++k) {
            int cc = c2 + 4 * k;
            outpre[cc * NODES + n] = tile[cc * 65 + j2];
        }
    }
    if (t < 64) {
        float s = reds[t][0] + reds[t][1] + reds[t][2] + reds[t][3];
        float q = redq[t][0] + redq[t][1] + redq[t][2] + redq[t][3];
        atomicAdd(&bn[t], s);
        atomicAdd(&bn[64 + t], q);
    }
}

// K4: per-channel affine from batch stats + PReLU, float4 per thread.
__global__ __launch_bounds__(256) void k_final(
        float* __restrict__ out, const float* __restrict__ bn,
        const float* __restrict__ gamma, const float* __restrict__ beta,
        const float* __restrict__ pa) {
    const int c = blockIdx.y;
    const int i4 = (blockIdx.x * 256 + threadIdx.x) * 4;
    const float invN = 1.f / (float)NODES;
    float mu = bn[c] * invN;
    float var = fmaxf(bn[64 + c] * invN - mu * mu, 0.f);
    float scale = gamma[c] * rsqrtf(var + BN_EPS);
    float shift = beta[c] - mu * scale;
    float a = pa[0];
    if (i4 < NODES) {   // NODES % 4 == 0 -> full float4 valid
        float4 y = *(float4*)(out + (size_t)c * NODES + i4);
        y.x = y.x * scale + shift; y.x = (y.x >= 0.f) ? y.x : a * y.x;
        y.y = y.y * scale + shift; y.y = (y.y >= 0.f) ? y.y : a * y.y;
        y.z = y.z * scale + shift; y.z = (y.z >= 0.f) ? y.z : a * y.z;
        y.w = y.w * scale + shift; y.w = (y.w >= 0.f) ? y.w : a * y.w;
        *(float4*)(out + (size_t)c * NODES + i4) = y;
    }
}

// Fallback (ws too small): atomic scatter, node-major sums (round-2 proven).
__global__ __launch_bounds__(256) void k_scatter(
        const float* __restrict__ Fn,
        const int* __restrict__ gidx, const int* __restrict__ ridx,
        float* __restrict__ sums, int* __restrict__ counts, int E) {
    const int wave = (int)((blockIdx.x * blockDim.x + threadIdx.x) >> 6);
    const int lane = threadIdx.x & 63;
    const int base = wave * 64;
    if (base >= E) return;
    const int nvalid = min(64, E - base);
    int g = 0, r = 0;
    if (lane < nvalid) {
        g = gidx[base + lane];
        r = ridx[base + lane];
        atomicAdd(&counts[r], 1);
    }
    for (int i = 0; i < nvalid; ++i) {
        int gg = __shfl(g, i);
        int rr = __shfl(r, i);
        float v = Fn[gg * 64 + lane];
        atomicAdd(&sums[rr * 64 + lane], v);
    }
}

extern "C" void kernel_launch(void* const* d_in, const int* in_sizes, int n_in,
                              void* d_out, int out_size, void* d_ws, size_t ws_size,
                              hipStream_t stream) {
    const float* x     = (const float*)d_in[0];
    const float* w_v   = (const float*)d_in[1];
    const float* w_n   = (const float*)d_in[2];
    const float* gamma = (const float*)d_in[3];
    const float* beta  = (const float*)d_in[4];
    const float* pa    = (const float*)d_in[5];
    const int* ridx    = (const int*)d_in[6];
    const int* gidx    = (const int*)d_in[7];
    float* out = (float*)d_out;

    const int E = in_sizes[6];
    const long long N64 = (long long)NODES * 64;
    const int ntiles = (NODES + 63) / 64;
    const dim3 g4((NODES / 4 + 255) / 256, 64);   // float4 k_final

    // Main ws (words): meanx[N64] | packed[256*CAP] | cursor[256] | bn[128] |
    //                  nodestart[NODES] | cnt[NODES]  = 9,946,816 (39.8 MB)
    size_t need = ((size_t)N64 + (size_t)NB2 * CAP + NB2 + 128
                   + NODES + NODES) * 4;

    if (ws_size >= need) {
        float*    meanx     = (float*)d_ws;
        unsigned* packed    = (unsigned*)(meanx + N64);
        int*      cursor    = (int*)(packed + (size_t)NB2 * CAP);
        float*    bn        = (float*)(cursor + NB2);
        int*      nodestart = (int*)(bn + 128);
        int*      cntarr    = nodestart + NODES;
        unsigned* xb = (unsigned*)out;  // 12.8 MB bf16 x rows staged in d_out

        hipMemsetAsync(cursor, 0, (NB2 + 128) * sizeof(int), stream);
        k_place<<<256, 1024, 0, stream>>>(ridx, gidx, cursor, packed, E);
        k_xpose<<<ntiles, 256, 0, stream>>>(x, xb);
        k_sortb<<<NB2, 1024, 0, stream>>>(cursor, packed, nodestart, cntarr);
        k_segreduce<<<(NODES * 64 + 255) / 256, 256, 0, stream>>>(
            xb, packed, nodestart, cntarr, (float4*)meanx);
        k_combine128<<<ntiles, 256, 0, stream>>>(x, w_v, w_n, meanx, out, bn);
        k_final<<<g4, 256, 0, stream>>>(out, bn, gamma, beta, pa);
    } else {
        // Fallback: atomic-scatter path (26.0 MB ws), round-2 proven chain.
        float* sums   = (float*)d_ws;
        int*   counts = (int*)(sums + N64);
        float* bn     = (float*)(sums + N64 + NODES);
        float* Fn = out;

        hipMemsetAsync(sums, 0, (size_t)(N64 + NODES + 128) * sizeof(float),
                       stream);
        k_gemm_n<<<ntiles, 256, 0, stream>>>(x, w_n, Fn);
        k_scatter<<<(E + 255) / 256, 256, 0, stream>>>(Fn, gidx, ridx, sums,
                                                       counts, E);
        k_combine_fb<<<ntiles, 256, 0, stream>>>(x, w_v, sums, counts, 1, out, bn);
        k_final<<<g4, 256, 0, stream>>>(out, bn, gamma, beta, pa);
    }
}